// Round 11
// baseline (74.133 us; speedup 1.0000x reference)
//
#include <hip/hip_runtime.h>
#include <hip/hip_fp16.h>

// Butterfly: out = butterfly_mult_untied(twiddle, x) + bias
// x: (32768, 1024) f32; twiddle: (1, 10, 512, 2, 2) f32; bias: (1024,) f32
// Stage idx pairs n with n^(1<<idx); p_idx(n) = n with bit idx deleted;
// out(n) = t[p][i][i]*v(n) + t[p][i][1-i]*v(n^stride), i = bit idx of n.
//
// R9: 1-block prep kernel materializes packed per-thread coeffs into d_ws
//     ([group][tid], 40 KB); main kernel preloads via 10 coalesced uint4 loads.
//     __syncthreads per batch (drain is cheap: in-flight ops are old by then).
// R11: prefetch for batch b+1 issued at the TOP of batch b (right after the
//     consume), pinned with sched_barrier(0). Load-to-use distance becomes
//     ~stages+barrier+epilogue (>= HBM latency) instead of ~150 cy -> kills
//     the per-batch head stall. (R10's lds_barrier regressed: FETCH 66->83 MB,
//     L3-timing sensitivity; reverted.)
//
// Main kernel numerics = R7 (proven, absmax 0.125):
//   256 threads, thread owns n = tid*4+e; stages 0-1 intra-thread;
//   stages 2-7 DPP/permlane (VALU); stages 8-9 merged 4-term combo via one
//   LDS roundtrip + barrier; packed __half2 coeffs (lo=self, hi=partner).

#define RPB 16        // rows per block
#define RB  4         // rows per batch
#define NB  (RPB/RB)  // batches per block
#define WS_WORDS 40   // u32 coeff words per thread: 32 hc + 4 hd01 + 4 hd23

typedef int v2i __attribute__((ext_vector_type(2)));

template<int CTRL>
__device__ __forceinline__ float dppf(float v) {
    const int i = __float_as_int(v);
    return __int_as_float(__builtin_amdgcn_update_dpp(i, i, CTRL, 0xF, 0xF, true));
}

__device__ __forceinline__ float xor4f(float v, bool b4) {
    const float shl = dppf<0x104>(v);  // src p+4
    const float shr = dppf<0x114>(v);  // src p-4
    return b4 ? shr : shl;
}

__device__ __forceinline__ float xor16f(float v, bool hi16) {
#if __has_builtin(__builtin_amdgcn_permlane16_swap)
    const int i = __float_as_int(v);
    const v2i p = __builtin_amdgcn_permlane16_swap(i, i, false, false);
    return __int_as_float(hi16 ? p[0] : p[1]);
#else
    return __int_as_float(__builtin_amdgcn_ds_swizzle(__float_as_int(v), 0x401F));
#endif
}

__device__ __forceinline__ float xor32f(float v, bool hi32, int bpaddr) {
#if __has_builtin(__builtin_amdgcn_permlane32_swap)
    const int i = __float_as_int(v);
    const v2i p = __builtin_amdgcn_permlane32_swap(i, i, false, false);
    return __int_as_float(hi32 ? p[0] : p[1]);
#else
    return __int_as_float(__builtin_amdgcn_ds_bpermute(bpaddr, __float_as_int(v)));
#endif
}

__device__ __forceinline__ float flo(__half2 h) { return __half2float(__low2half(h)); }
__device__ __forceinline__ float fhi(__half2 h) { return __half2float(__high2half(h)); }
__device__ __forceinline__ unsigned h2u(__half2 h) {
    union { __half2 h; unsigned u; } c; c.h = h; return c.u;
}
__device__ __forceinline__ __half2 u2h(unsigned u) {
    union { __half2 h; unsigned u; } c; c.u = u; return c.h;
}

// Shared coefficient math (per-thread, gather from twiddle).
__device__ __forceinline__ void compute_coeffs(const float* __restrict__ tw, int tid,
                                               unsigned w[WS_WORDS]) {
    const int n0 = tid * 4;
#pragma unroll
    for (int idx = 0; idx < 8; ++idx) {
        const int stride = 1 << idx;
#pragma unroll
        for (int e = 0; e < 4; ++e) {
            const int n = n0 + e;
            const int p = ((n >> (idx + 1)) << idx) | (n & (stride - 1));
            const int i = (n >> idx) & 1;
            const float* tp = tw + idx * 2048 + p * 4 + i * 2;
            w[idx * 4 + e] = h2u(__halves2half2(__float2half(tp[i]), __float2half(tp[1 - i])));
        }
    }
    const int b8 = (tid >> 6) & 1;
    const int b9 = (tid >> 7) & 1;
#pragma unroll
    for (int e = 0; e < 4; ++e) {
        const int n   = n0 + e;
        const int low = n & 255;
        const int p9  = n & 511;
        const float* t9p = tw + 9 * 2048 + p9 * 4 + b9 * 2;
        const float A = t9p[b9], Bv = t9p[1 - b9];
        const float* t8a = tw + 8 * 2048 + (( b9      << 8) | low) * 4 + b8 * 2;
        const float* t8b = tw + 8 * 2048 + (((1 - b9) << 8) | low) * 4 + b8 * 2;
        w[32 + e] = h2u(__halves2half2(__float2half(A * t8a[b8]),  __float2half(A * t8a[1 - b8])));
        w[36 + e] = h2u(__halves2half2(__float2half(Bv * t8b[b8]), __float2half(Bv * t8b[1 - b8])));
    }
}

// Prep: 1 block x 256 threads. ws layout: uint4 table[10][256] (group-major).
__global__ void coeff_prep_kernel(const float* __restrict__ tw, unsigned* __restrict__ ws) {
    const int tid = threadIdx.x;
    unsigned w[WS_WORDS];
    compute_coeffs(tw, tid, w);
    uint4* t4 = reinterpret_cast<uint4*>(ws);
#pragma unroll
    for (int g = 0; g < WS_WORDS / 4; ++g)
        t4[g * 256 + tid] = make_uint4(w[g * 4], w[g * 4 + 1], w[g * 4 + 2], w[g * 4 + 3]);
}

template<bool USE_WS>
__global__ __launch_bounds__(256, 4)
void butterfly_kernel(const float* __restrict__ x,
                      const float* __restrict__ tw,
                      const float* __restrict__ bias,
                      float* __restrict__ out,
                      const unsigned* __restrict__ ws) {
    __shared__ float4 lds[2][RB][256];
    const int tid  = threadIdx.x;
    const int lane = tid & 63;
    const bool b4set = (lane & 4)  != 0;
    const bool hi16  = (lane & 16) != 0;
    const bool hi32  = (lane & 32) != 0;
    const int bpaddr = ((lane ^ 32) & 63) << 2;
    const int n0 = tid * 4;
    const int rowbase = blockIdx.x * RPB;

    // Batch-0 loads first: latency overlaps the (tiny) coeff preload.
    float4 cur[RB];
#pragma unroll
    for (int r = 0; r < RB; ++r)
        cur[r] = *reinterpret_cast<const float4*>(x + (size_t)(rowbase + r) * 1024 + n0);

    // ---- Coefficient preload ----
    unsigned w[WS_WORDS];
    if constexpr (USE_WS) {
        const uint4* t4 = reinterpret_cast<const uint4*>(ws);
#pragma unroll
        for (int g = 0; g < WS_WORDS / 4; ++g) {
            const uint4 q = t4[g * 256 + tid];
            w[g * 4] = q.x; w[g * 4 + 1] = q.y; w[g * 4 + 2] = q.z; w[g * 4 + 3] = q.w;
        }
    } else {
        compute_coeffs(tw, tid, w);  // fallback: self-contained gather
    }
    __half2 hc[8][4], hd01[4], hd23[4];
#pragma unroll
    for (int idx = 0; idx < 8; ++idx)
#pragma unroll
        for (int e = 0; e < 4; ++e)
            hc[idx][e] = u2h(w[idx * 4 + e]);
#pragma unroll
    for (int e = 0; e < 4; ++e) { hd01[e] = u2h(w[32 + e]); hd23[e] = u2h(w[36 + e]); }
    float4 b4v = *reinterpret_cast<const float4*>(bias + n0);

    // Pin coefficients: forbid per-row rematerialization.
#pragma unroll
    for (int idx = 0; idx < 8; ++idx)
#pragma unroll
        for (int e = 0; e < 4; ++e)
            asm volatile("" : "+v"(hc[idx][e]));
#pragma unroll
    for (int e = 0; e < 4; ++e)
        asm volatile("" : "+v"(hd01[e]), "+v"(hd23[e]));
    asm volatile("" : "+v"(b4v.x), "+v"(b4v.y), "+v"(b4v.z), "+v"(b4v.w));

    for (int b = 0; b < NB; ++b) {
        float v[RB][4];
#pragma unroll
        for (int r = 0; r < RB; ++r) {
            v[r][0] = cur[r].x; v[r][1] = cur[r].y; v[r][2] = cur[r].z; v[r][3] = cur[r].w;
        }
        // R11: issue next batch's loads NOW (top of batch) so they have the
        // whole stage section + barrier to land. Pin issue order so the
        // scheduler can't sink them toward their use.
        if (b + 1 < NB) {
#pragma unroll
            for (int r = 0; r < RB; ++r)
                cur[r] = *reinterpret_cast<const float4*>(
                    x + (size_t)(rowbase + (b + 1) * RB + r) * 1024 + n0);
            __builtin_amdgcn_sched_barrier(0);
        }

        // stage 0 (stride 1): pairs (e0,e1),(e2,e3)
#pragma unroll
        for (int r = 0; r < RB; ++r) {
            float a0 = flo(hc[0][0]) * v[r][0] + fhi(hc[0][0]) * v[r][1];
            float a1 = flo(hc[0][1]) * v[r][1] + fhi(hc[0][1]) * v[r][0];
            float a2 = flo(hc[0][2]) * v[r][2] + fhi(hc[0][2]) * v[r][3];
            float a3 = flo(hc[0][3]) * v[r][3] + fhi(hc[0][3]) * v[r][2];
            v[r][0] = a0; v[r][1] = a1; v[r][2] = a2; v[r][3] = a3;
        }
        // stage 1 (stride 2): pairs (e0,e2),(e1,e3)
#pragma unroll
        for (int r = 0; r < RB; ++r) {
            float a0 = flo(hc[1][0]) * v[r][0] + fhi(hc[1][0]) * v[r][2];
            float a1 = flo(hc[1][1]) * v[r][1] + fhi(hc[1][1]) * v[r][3];
            float a2 = flo(hc[1][2]) * v[r][2] + fhi(hc[1][2]) * v[r][0];
            float a3 = flo(hc[1][3]) * v[r][3] + fhi(hc[1][3]) * v[r][1];
            v[r][0] = a0; v[r][1] = a1; v[r][2] = a2; v[r][3] = a3;
        }
        // stage 2: lane^1 (quad_perm [1,0,3,2])
#pragma unroll
        for (int r = 0; r < RB; ++r)
#pragma unroll
            for (int e = 0; e < 4; ++e) {
                const float o = dppf<0xB1>(v[r][e]);
                v[r][e] = flo(hc[2][e]) * v[r][e] + fhi(hc[2][e]) * o;
            }
        // stage 3: lane^2 (quad_perm [2,3,0,1])
#pragma unroll
        for (int r = 0; r < RB; ++r)
#pragma unroll
            for (int e = 0; e < 4; ++e) {
                const float o = dppf<0x4E>(v[r][e]);
                v[r][e] = flo(hc[3][e]) * v[r][e] + fhi(hc[3][e]) * o;
            }
        // stage 4: lane^4 (two DPP shifts + select)
#pragma unroll
        for (int r = 0; r < RB; ++r)
#pragma unroll
            for (int e = 0; e < 4; ++e) {
                const float o = xor4f(v[r][e], b4set);
                v[r][e] = flo(hc[4][e]) * v[r][e] + fhi(hc[4][e]) * o;
            }
        // stage 5: lane^8 (row_ror:8)
#pragma unroll
        for (int r = 0; r < RB; ++r)
#pragma unroll
            for (int e = 0; e < 4; ++e) {
                const float o = dppf<0x128>(v[r][e]);
                v[r][e] = flo(hc[5][e]) * v[r][e] + fhi(hc[5][e]) * o;
            }
        // stage 6: lane^16 (permlane16_swap)
#pragma unroll
        for (int r = 0; r < RB; ++r)
#pragma unroll
            for (int e = 0; e < 4; ++e) {
                const float o = xor16f(v[r][e], hi16);
                v[r][e] = flo(hc[6][e]) * v[r][e] + fhi(hc[6][e]) * o;
            }
        // stage 7: lane^32 (permlane32_swap)
#pragma unroll
        for (int r = 0; r < RB; ++r)
#pragma unroll
            for (int e = 0; e < 4; ++e) {
                const float o = xor32f(v[r][e], hi32, bpaddr);
                v[r][e] = flo(hc[7][e]) * v[r][e] + fhi(hc[7][e]) * o;
            }

        // merged stages 8+9: one LDS roundtrip, one barrier per batch (4 rows).
        const int buf = b & 1;
#pragma unroll
        for (int r = 0; r < RB; ++r)
            lds[buf][r][tid] = make_float4(v[r][0], v[r][1], v[r][2], v[r][3]);
        __syncthreads();

#pragma unroll
        for (int r = 0; r < RB; ++r) {
            const float4 o64  = lds[buf][r][tid ^ 64];
            const float4 o128 = lds[buf][r][tid ^ 128];
            const float4 o192 = lds[buf][r][tid ^ 192];
            float4 s;
            s.x = flo(hd01[0])*v[r][0] + fhi(hd01[0])*o64.x + flo(hd23[0])*o128.x + fhi(hd23[0])*o192.x + b4v.x;
            s.y = flo(hd01[1])*v[r][1] + fhi(hd01[1])*o64.y + flo(hd23[1])*o128.y + fhi(hd23[1])*o192.y + b4v.y;
            s.z = flo(hd01[2])*v[r][2] + fhi(hd01[2])*o64.z + flo(hd23[2])*o128.z + fhi(hd23[2])*o192.z + b4v.z;
            s.w = flo(hd01[3])*v[r][3] + fhi(hd01[3])*o64.w + flo(hd23[3])*o128.w + fhi(hd23[3])*o192.w + b4v.w;
            *reinterpret_cast<float4*>(out + (size_t)(rowbase + b * RB + r) * 1024 + n0) = s;
        }
        // Race-freedom (R3..R9 argument): reads of lds[buf] (batch b) precede
        // the __syncthreads of batch b+1; writes to lds[buf] recur at batch b+2,
        // after that barrier. No overlap.
    }
}

extern "C" void kernel_launch(void* const* d_in, const int* in_sizes, int n_in,
                              void* d_out, int out_size, void* d_ws, size_t ws_size,
                              hipStream_t stream) {
    const float* x    = (const float*)d_in[0];
    const float* tw   = (const float*)d_in[1];
    const float* bias = (const float*)d_in[2];
    float* outp = (float*)d_out;
    unsigned* ws = (unsigned*)d_ws;
    dim3 grid(32768 / RPB);   // 2048 blocks
    dim3 block(256);
    if (ws_size >= WS_WORDS * 256 * sizeof(unsigned)) {
        hipLaunchKernelGGL(coeff_prep_kernel, dim3(1), block, 0, stream, tw, ws);
        hipLaunchKernelGGL((butterfly_kernel<true>), grid, block, 0, stream,
                           x, tw, bias, outp, ws);
    } else {
        hipLaunchKernelGGL((butterfly_kernel<false>), grid, block, 0, stream,
                           x, tw, bias, outp, ws);
    }
}

// Round 13
// 56.845 us; speedup vs baseline: 1.3041x; 1.3041x over previous
//
#include <hip/hip_runtime.h>
#include <hip/hip_fp16.h>

// Butterfly: out = butterfly_mult_untied(twiddle, x) + bias
// x: (32768, 1024) f32; twiddle: (1, 10, 512, 2, 2) f32; bias: (1024,) f32
// Stage idx pairs n with n^(1<<idx); p_idx(n) = n with bit idx deleted;
// out(n) = t[p][i][i]*v(n) + t[p][i][1-i]*v(n^stride), i = bit idx of n.
//
// R9 (60.3 us, best): 1-block prep kernel materializes packed per-thread coeffs
//     into d_ws ([group][tid], 40 KB); main kernel preloads via 10 coalesced
//     uint4 loads; prefetch issued after the barrier (R10/R11 reorderings both
//     regressed via FETCH 66->85 MB: the kernel is L3-residency sensitive).
// R12/R13: nontemporal OUTPUT stores. x(128MB)+out(128MB) exactly fill the
//     256MB L3; out write-allocations evict x between graph replays (FETCH=66MB
//     of re-reads). out is never re-read -> nt stores keep x L3-resident.
//     R13 fixes the R12 compile error: __builtin_nontemporal_store requires a
//     native vector type, not HIP_vector_type float4 -> use ext_vector f32x4.
//
// Main kernel numerics = R7 (proven, absmax 0.125):
//   256 threads, thread owns n = tid*4+e; stages 0-1 intra-thread;
//   stages 2-7 DPP/permlane (VALU); stages 8-9 merged 4-term combo via one
//   LDS roundtrip + barrier; packed __half2 coeffs (lo=self, hi=partner).

#define RPB 16        // rows per block
#define RB  4         // rows per batch
#define NB  (RPB/RB)  // batches per block
#define WS_WORDS 40   // u32 coeff words per thread: 32 hc + 4 hd01 + 4 hd23

typedef int v2i __attribute__((ext_vector_type(2)));
typedef float f32x4 __attribute__((ext_vector_type(4)));  // nt-store-compatible

template<int CTRL>
__device__ __forceinline__ float dppf(float v) {
    const int i = __float_as_int(v);
    return __int_as_float(__builtin_amdgcn_update_dpp(i, i, CTRL, 0xF, 0xF, true));
}

__device__ __forceinline__ float xor4f(float v, bool b4) {
    const float shl = dppf<0x104>(v);  // src p+4
    const float shr = dppf<0x114>(v);  // src p-4
    return b4 ? shr : shl;
}

__device__ __forceinline__ float xor16f(float v, bool hi16) {
#if __has_builtin(__builtin_amdgcn_permlane16_swap)
    const int i = __float_as_int(v);
    const v2i p = __builtin_amdgcn_permlane16_swap(i, i, false, false);
    return __int_as_float(hi16 ? p[0] : p[1]);
#else
    return __int_as_float(__builtin_amdgcn_ds_swizzle(__float_as_int(v), 0x401F));
#endif
}

__device__ __forceinline__ float xor32f(float v, bool hi32, int bpaddr) {
#if __has_builtin(__builtin_amdgcn_permlane32_swap)
    const int i = __float_as_int(v);
    const v2i p = __builtin_amdgcn_permlane32_swap(i, i, false, false);
    return __int_as_float(hi32 ? p[0] : p[1]);
#else
    return __int_as_float(__builtin_amdgcn_ds_bpermute(bpaddr, __float_as_int(v)));
#endif
}

__device__ __forceinline__ float flo(__half2 h) { return __half2float(__low2half(h)); }
__device__ __forceinline__ float fhi(__half2 h) { return __half2float(__high2half(h)); }
__device__ __forceinline__ unsigned h2u(__half2 h) {
    union { __half2 h; unsigned u; } c; c.h = h; return c.u;
}
__device__ __forceinline__ __half2 u2h(unsigned u) {
    union { __half2 h; unsigned u; } c; c.u = u; return c.h;
}

// Shared coefficient math (per-thread, gather from twiddle).
__device__ __forceinline__ void compute_coeffs(const float* __restrict__ tw, int tid,
                                               unsigned w[WS_WORDS]) {
    const int n0 = tid * 4;
#pragma unroll
    for (int idx = 0; idx < 8; ++idx) {
        const int stride = 1 << idx;
#pragma unroll
        for (int e = 0; e < 4; ++e) {
            const int n = n0 + e;
            const int p = ((n >> (idx + 1)) << idx) | (n & (stride - 1));
            const int i = (n >> idx) & 1;
            const float* tp = tw + idx * 2048 + p * 4 + i * 2;
            w[idx * 4 + e] = h2u(__halves2half2(__float2half(tp[i]), __float2half(tp[1 - i])));
        }
    }
    const int b8 = (tid >> 6) & 1;
    const int b9 = (tid >> 7) & 1;
#pragma unroll
    for (int e = 0; e < 4; ++e) {
        const int n   = n0 + e;
        const int low = n & 255;
        const int p9  = n & 511;
        const float* t9p = tw + 9 * 2048 + p9 * 4 + b9 * 2;
        const float A = t9p[b9], Bv = t9p[1 - b9];
        const float* t8a = tw + 8 * 2048 + (( b9      << 8) | low) * 4 + b8 * 2;
        const float* t8b = tw + 8 * 2048 + (((1 - b9) << 8) | low) * 4 + b8 * 2;
        w[32 + e] = h2u(__halves2half2(__float2half(A * t8a[b8]),  __float2half(A * t8a[1 - b8])));
        w[36 + e] = h2u(__halves2half2(__float2half(Bv * t8b[b8]), __float2half(Bv * t8b[1 - b8])));
    }
}

// Prep: 1 block x 256 threads. ws layout: uint4 table[10][256] (group-major).
__global__ void coeff_prep_kernel(const float* __restrict__ tw, unsigned* __restrict__ ws) {
    const int tid = threadIdx.x;
    unsigned w[WS_WORDS];
    compute_coeffs(tw, tid, w);
    uint4* t4 = reinterpret_cast<uint4*>(ws);
#pragma unroll
    for (int g = 0; g < WS_WORDS / 4; ++g)
        t4[g * 256 + tid] = make_uint4(w[g * 4], w[g * 4 + 1], w[g * 4 + 2], w[g * 4 + 3]);
}

template<bool USE_WS>
__global__ __launch_bounds__(256, 4)
void butterfly_kernel(const float* __restrict__ x,
                      const float* __restrict__ tw,
                      const float* __restrict__ bias,
                      float* __restrict__ out,
                      const unsigned* __restrict__ ws) {
    __shared__ float4 lds[2][RB][256];
    const int tid  = threadIdx.x;
    const int lane = tid & 63;
    const bool b4set = (lane & 4)  != 0;
    const bool hi16  = (lane & 16) != 0;
    const bool hi32  = (lane & 32) != 0;
    const int bpaddr = ((lane ^ 32) & 63) << 2;
    const int n0 = tid * 4;
    const int rowbase = blockIdx.x * RPB;

    // Batch-0 loads first: latency overlaps the (tiny) coeff preload.
    float4 cur[RB];
#pragma unroll
    for (int r = 0; r < RB; ++r)
        cur[r] = *reinterpret_cast<const float4*>(x + (size_t)(rowbase + r) * 1024 + n0);

    // ---- Coefficient preload ----
    unsigned w[WS_WORDS];
    if constexpr (USE_WS) {
        const uint4* t4 = reinterpret_cast<const uint4*>(ws);
#pragma unroll
        for (int g = 0; g < WS_WORDS / 4; ++g) {
            const uint4 q = t4[g * 256 + tid];
            w[g * 4] = q.x; w[g * 4 + 1] = q.y; w[g * 4 + 2] = q.z; w[g * 4 + 3] = q.w;
        }
    } else {
        compute_coeffs(tw, tid, w);  // fallback: self-contained gather
    }
    __half2 hc[8][4], hd01[4], hd23[4];
#pragma unroll
    for (int idx = 0; idx < 8; ++idx)
#pragma unroll
        for (int e = 0; e < 4; ++e)
            hc[idx][e] = u2h(w[idx * 4 + e]);
#pragma unroll
    for (int e = 0; e < 4; ++e) { hd01[e] = u2h(w[32 + e]); hd23[e] = u2h(w[36 + e]); }
    float4 b4v = *reinterpret_cast<const float4*>(bias + n0);

    // Pin coefficients: forbid per-row rematerialization.
#pragma unroll
    for (int idx = 0; idx < 8; ++idx)
#pragma unroll
        for (int e = 0; e < 4; ++e)
            asm volatile("" : "+v"(hc[idx][e]));
#pragma unroll
    for (int e = 0; e < 4; ++e)
        asm volatile("" : "+v"(hd01[e]), "+v"(hd23[e]));
    asm volatile("" : "+v"(b4v.x), "+v"(b4v.y), "+v"(b4v.z), "+v"(b4v.w));

    for (int b = 0; b < NB; ++b) {
        float v[RB][4];
#pragma unroll
        for (int r = 0; r < RB; ++r) {
            v[r][0] = cur[r].x; v[r][1] = cur[r].y; v[r][2] = cur[r].z; v[r][3] = cur[r].w;
        }
        // stage 0 (stride 1): pairs (e0,e1),(e2,e3)
#pragma unroll
        for (int r = 0; r < RB; ++r) {
            float a0 = flo(hc[0][0]) * v[r][0] + fhi(hc[0][0]) * v[r][1];
            float a1 = flo(hc[0][1]) * v[r][1] + fhi(hc[0][1]) * v[r][0];
            float a2 = flo(hc[0][2]) * v[r][2] + fhi(hc[0][2]) * v[r][3];
            float a3 = flo(hc[0][3]) * v[r][3] + fhi(hc[0][3]) * v[r][2];
            v[r][0] = a0; v[r][1] = a1; v[r][2] = a2; v[r][3] = a3;
        }
        // stage 1 (stride 2): pairs (e0,e2),(e1,e3)
#pragma unroll
        for (int r = 0; r < RB; ++r) {
            float a0 = flo(hc[1][0]) * v[r][0] + fhi(hc[1][0]) * v[r][2];
            float a1 = flo(hc[1][1]) * v[r][1] + fhi(hc[1][1]) * v[r][3];
            float a2 = flo(hc[1][2]) * v[r][2] + fhi(hc[1][2]) * v[r][0];
            float a3 = flo(hc[1][3]) * v[r][3] + fhi(hc[1][3]) * v[r][1];
            v[r][0] = a0; v[r][1] = a1; v[r][2] = a2; v[r][3] = a3;
        }
        // stage 2: lane^1 (quad_perm [1,0,3,2])
#pragma unroll
        for (int r = 0; r < RB; ++r)
#pragma unroll
            for (int e = 0; e < 4; ++e) {
                const float o = dppf<0xB1>(v[r][e]);
                v[r][e] = flo(hc[2][e]) * v[r][e] + fhi(hc[2][e]) * o;
            }
        // stage 3: lane^2 (quad_perm [2,3,0,1])
#pragma unroll
        for (int r = 0; r < RB; ++r)
#pragma unroll
            for (int e = 0; e < 4; ++e) {
                const float o = dppf<0x4E>(v[r][e]);
                v[r][e] = flo(hc[3][e]) * v[r][e] + fhi(hc[3][e]) * o;
            }
        // stage 4: lane^4 (two DPP shifts + select)
#pragma unroll
        for (int r = 0; r < RB; ++r)
#pragma unroll
            for (int e = 0; e < 4; ++e) {
                const float o = xor4f(v[r][e], b4set);
                v[r][e] = flo(hc[4][e]) * v[r][e] + fhi(hc[4][e]) * o;
            }
        // stage 5: lane^8 (row_ror:8)
#pragma unroll
        for (int r = 0; r < RB; ++r)
#pragma unroll
            for (int e = 0; e < 4; ++e) {
                const float o = dppf<0x128>(v[r][e]);
                v[r][e] = flo(hc[5][e]) * v[r][e] + fhi(hc[5][e]) * o;
            }
        // stage 6: lane^16 (permlane16_swap)
#pragma unroll
        for (int r = 0; r < RB; ++r)
#pragma unroll
            for (int e = 0; e < 4; ++e) {
                const float o = xor16f(v[r][e], hi16);
                v[r][e] = flo(hc[6][e]) * v[r][e] + fhi(hc[6][e]) * o;
            }
        // stage 7: lane^32 (permlane32_swap)
#pragma unroll
        for (int r = 0; r < RB; ++r)
#pragma unroll
            for (int e = 0; e < 4; ++e) {
                const float o = xor32f(v[r][e], hi32, bpaddr);
                v[r][e] = flo(hc[7][e]) * v[r][e] + fhi(hc[7][e]) * o;
            }
        // merged stages 8+9: one LDS roundtrip, one barrier per batch (4 rows).
        const int buf = b & 1;
#pragma unroll
        for (int r = 0; r < RB; ++r)
            lds[buf][r][tid] = make_float4(v[r][0], v[r][1], v[r][2], v[r][3]);
        __syncthreads();

        // Prefetch next batch (R9 position: after the barrier; R10/R11 moves
        // both regressed via L3-residency loss).
        if (b + 1 < NB) {
#pragma unroll
            for (int r = 0; r < RB; ++r)
                cur[r] = *reinterpret_cast<const float4*>(
                    x + (size_t)(rowbase + (b + 1) * RB + r) * 1024 + n0);
        }

#pragma unroll
        for (int r = 0; r < RB; ++r) {
            const float4 o64  = lds[buf][r][tid ^ 64];
            const float4 o128 = lds[buf][r][tid ^ 128];
            const float4 o192 = lds[buf][r][tid ^ 192];
            f32x4 s;
            s.x = flo(hd01[0])*v[r][0] + fhi(hd01[0])*o64.x + flo(hd23[0])*o128.x + fhi(hd23[0])*o192.x + b4v.x;
            s.y = flo(hd01[1])*v[r][1] + fhi(hd01[1])*o64.y + flo(hd23[1])*o128.y + fhi(hd23[1])*o192.y + b4v.y;
            s.z = flo(hd01[2])*v[r][2] + fhi(hd01[2])*o64.z + flo(hd23[2])*o128.z + fhi(hd23[2])*o192.z + b4v.z;
            s.w = flo(hd01[3])*v[r][3] + fhi(hd01[3])*o64.w + flo(hd23[3])*o128.w + fhi(hd23[3])*o192.w + b4v.w;
            // R13: nontemporal store (native vector type) -- out doesn't evict
            // x from L3 between graph replays.
            __builtin_nontemporal_store(
                s, reinterpret_cast<f32x4*>(out + (size_t)(rowbase + b * RB + r) * 1024 + n0));
        }
        // Race-freedom (R3..R9 argument): reads of lds[buf] (batch b) precede
        // the __syncthreads of batch b+1; writes to lds[buf] recur at batch b+2,
        // after that barrier. No overlap.
    }
}

extern "C" void kernel_launch(void* const* d_in, const int* in_sizes, int n_in,
                              void* d_out, int out_size, void* d_ws, size_t ws_size,
                              hipStream_t stream) {
    const float* x    = (const float*)d_in[0];
    const float* tw   = (const float*)d_in[1];
    const float* bias = (const float*)d_in[2];
    float* outp = (float*)d_out;
    unsigned* ws = (unsigned*)d_ws;
    dim3 grid(32768 / RPB);   // 2048 blocks
    dim3 block(256);
    if (ws_size >= WS_WORDS * 256 * sizeof(unsigned)) {
        hipLaunchKernelGGL(coeff_prep_kernel, dim3(1), block, 0, stream, tw, ws);
        hipLaunchKernelGGL((butterfly_kernel<true>), grid, block, 0, stream,
                           x, tw, bias, outp, ws);
    } else {
        hipLaunchKernelGGL((butterfly_kernel<false>), grid, block, 0, stream,
                           x, tw, bias, outp, ws);
    }
}

// Round 14
// 56.813 us; speedup vs baseline: 1.3049x; 1.0006x over previous
//
#include <hip/hip_runtime.h>
#include <hip/hip_fp16.h>

// Butterfly: out = butterfly_mult_untied(twiddle, x) + bias
// x: (32768, 1024) f32; twiddle: (1, 10, 512, 2, 2) f32; bias: (1024,) f32
// Stage idx pairs n with n^(1<<idx); p_idx(n) = n with bit idx deleted;
// out(n) = t[p][i][i]*v(n) + t[p][i][1-i]*v(n^stride), i = bit idx of n.
//
// R9:  prep kernel materializes packed per-thread coeffs into d_ws (40 KB);
//      main kernel preloads via 10 coalesced uint4 loads.  (60.3 us)
// R13: nontemporal output stores (skip write-allocate path).  (56.8 us)
// R14: pins moved INSIDE the batch loop (3 grouped asm statements). The
//      once-before-loop pins let the allocator park the 44 loop-invariant
//      coeffs in AGPRs (unified file: 64 VGPR + ~112 AGPR = 176 regs/wave ->
//      2.85 waves/SIMD, plus v_accvgpr_read on the hot path). In-loop pins
//      make AGPR shuttling strictly unprofitable -> coeffs stay in VGPRs,
//      total ~100 < 128 cap -> 4 waves/SIMD.
//
// Main kernel numerics = R7 (proven, absmax 0.125):
//   256 threads, thread owns n = tid*4+e; stages 0-1 intra-thread;
//   stages 2-7 DPP/permlane (VALU); stages 8-9 merged 4-term combo via one
//   LDS roundtrip + barrier; packed __half2 coeffs (lo=self, hi=partner).

#define RPB 16        // rows per block
#define RB  4         // rows per batch
#define NB  (RPB/RB)  // batches per block
#define WS_WORDS 40   // u32 coeff words per thread: 32 hc + 4 hd01 + 4 hd23

typedef int v2i __attribute__((ext_vector_type(2)));
typedef float f32x4 __attribute__((ext_vector_type(4)));  // nt-store-compatible

template<int CTRL>
__device__ __forceinline__ float dppf(float v) {
    const int i = __float_as_int(v);
    return __int_as_float(__builtin_amdgcn_update_dpp(i, i, CTRL, 0xF, 0xF, true));
}

__device__ __forceinline__ float xor4f(float v, bool b4) {
    const float shl = dppf<0x104>(v);  // src p+4
    const float shr = dppf<0x114>(v);  // src p-4
    return b4 ? shr : shl;
}

__device__ __forceinline__ float xor16f(float v, bool hi16) {
#if __has_builtin(__builtin_amdgcn_permlane16_swap)
    const int i = __float_as_int(v);
    const v2i p = __builtin_amdgcn_permlane16_swap(i, i, false, false);
    return __int_as_float(hi16 ? p[0] : p[1]);
#else
    return __int_as_float(__builtin_amdgcn_ds_swizzle(__float_as_int(v), 0x401F));
#endif
}

__device__ __forceinline__ float xor32f(float v, bool hi32, int bpaddr) {
#if __has_builtin(__builtin_amdgcn_permlane32_swap)
    const int i = __float_as_int(v);
    const v2i p = __builtin_amdgcn_permlane32_swap(i, i, false, false);
    return __int_as_float(hi32 ? p[0] : p[1]);
#else
    return __int_as_float(__builtin_amdgcn_ds_bpermute(bpaddr, __float_as_int(v)));
#endif
}

__device__ __forceinline__ float flo(__half2 h) { return __half2float(__low2half(h)); }
__device__ __forceinline__ float fhi(__half2 h) { return __half2float(__high2half(h)); }
__device__ __forceinline__ unsigned h2u(__half2 h) {
    union { __half2 h; unsigned u; } c; c.h = h; return c.u;
}
__device__ __forceinline__ __half2 u2h(unsigned u) {
    union { __half2 h; unsigned u; } c; c.u = u; return c.h;
}

// Shared coefficient math (per-thread, gather from twiddle).
__device__ __forceinline__ void compute_coeffs(const float* __restrict__ tw, int tid,
                                               unsigned w[WS_WORDS]) {
    const int n0 = tid * 4;
#pragma unroll
    for (int idx = 0; idx < 8; ++idx) {
        const int stride = 1 << idx;
#pragma unroll
        for (int e = 0; e < 4; ++e) {
            const int n = n0 + e;
            const int p = ((n >> (idx + 1)) << idx) | (n & (stride - 1));
            const int i = (n >> idx) & 1;
            const float* tp = tw + idx * 2048 + p * 4 + i * 2;
            w[idx * 4 + e] = h2u(__halves2half2(__float2half(tp[i]), __float2half(tp[1 - i])));
        }
    }
    const int b8 = (tid >> 6) & 1;
    const int b9 = (tid >> 7) & 1;
#pragma unroll
    for (int e = 0; e < 4; ++e) {
        const int n   = n0 + e;
        const int low = n & 255;
        const int p9  = n & 511;
        const float* t9p = tw + 9 * 2048 + p9 * 4 + b9 * 2;
        const float A = t9p[b9], Bv = t9p[1 - b9];
        const float* t8a = tw + 8 * 2048 + (( b9      << 8) | low) * 4 + b8 * 2;
        const float* t8b = tw + 8 * 2048 + (((1 - b9) << 8) | low) * 4 + b8 * 2;
        w[32 + e] = h2u(__halves2half2(__float2half(A * t8a[b8]),  __float2half(A * t8a[1 - b8])));
        w[36 + e] = h2u(__halves2half2(__float2half(Bv * t8b[b8]), __float2half(Bv * t8b[1 - b8])));
    }
}

// Prep: 1 block x 256 threads. ws layout: uint4 table[10][256] (group-major).
__global__ void coeff_prep_kernel(const float* __restrict__ tw, unsigned* __restrict__ ws) {
    const int tid = threadIdx.x;
    unsigned w[WS_WORDS];
    compute_coeffs(tw, tid, w);
    uint4* t4 = reinterpret_cast<uint4*>(ws);
#pragma unroll
    for (int g = 0; g < WS_WORDS / 4; ++g)
        t4[g * 256 + tid] = make_uint4(w[g * 4], w[g * 4 + 1], w[g * 4 + 2], w[g * 4 + 3]);
}

template<bool USE_WS>
__global__ __launch_bounds__(256, 4)
void butterfly_kernel(const float* __restrict__ x,
                      const float* __restrict__ tw,
                      const float* __restrict__ bias,
                      float* __restrict__ out,
                      const unsigned* __restrict__ ws) {
    __shared__ float4 lds[2][RB][256];
    const int tid  = threadIdx.x;
    const int lane = tid & 63;
    const bool b4set = (lane & 4)  != 0;
    const bool hi16  = (lane & 16) != 0;
    const bool hi32  = (lane & 32) != 0;
    const int bpaddr = ((lane ^ 32) & 63) << 2;
    const int n0 = tid * 4;
    const int rowbase = blockIdx.x * RPB;

    // Batch-0 loads first: latency overlaps the (tiny) coeff preload.
    float4 cur[RB];
#pragma unroll
    for (int r = 0; r < RB; ++r)
        cur[r] = *reinterpret_cast<const float4*>(x + (size_t)(rowbase + r) * 1024 + n0);

    // ---- Coefficient preload ----
    unsigned w[WS_WORDS];
    if constexpr (USE_WS) {
        const uint4* t4 = reinterpret_cast<const uint4*>(ws);
#pragma unroll
        for (int g = 0; g < WS_WORDS / 4; ++g) {
            const uint4 q = t4[g * 256 + tid];
            w[g * 4] = q.x; w[g * 4 + 1] = q.y; w[g * 4 + 2] = q.z; w[g * 4 + 3] = q.w;
        }
    } else {
        compute_coeffs(tw, tid, w);  // fallback: self-contained gather
    }
    __half2 hc[8][4], hd01[4], hd23[4];
#pragma unroll
    for (int idx = 0; idx < 8; ++idx)
#pragma unroll
        for (int e = 0; e < 4; ++e)
            hc[idx][e] = u2h(w[idx * 4 + e]);
#pragma unroll
    for (int e = 0; e < 4; ++e) { hd01[e] = u2h(w[32 + e]); hd23[e] = u2h(w[36 + e]); }
    float4 b4v = *reinterpret_cast<const float4*>(bias + n0);

    for (int b = 0; b < NB; ++b) {
        // R14: pin ALL coefficients in VGPRs at a point INSIDE every iteration.
        // Makes AGPR shuttling strictly unprofitable -> no AGPR shadow, no
        // v_accvgpr_read on the hot path. (<=16 operands per asm statement.)
        asm volatile("" : "+v"(hc[0][0]), "+v"(hc[0][1]), "+v"(hc[0][2]), "+v"(hc[0][3]),
                          "+v"(hc[1][0]), "+v"(hc[1][1]), "+v"(hc[1][2]), "+v"(hc[1][3]),
                          "+v"(hc[2][0]), "+v"(hc[2][1]), "+v"(hc[2][2]), "+v"(hc[2][3]),
                          "+v"(hc[3][0]), "+v"(hc[3][1]), "+v"(hc[3][2]), "+v"(hc[3][3]));
        asm volatile("" : "+v"(hc[4][0]), "+v"(hc[4][1]), "+v"(hc[4][2]), "+v"(hc[4][3]),
                          "+v"(hc[5][0]), "+v"(hc[5][1]), "+v"(hc[5][2]), "+v"(hc[5][3]),
                          "+v"(hc[6][0]), "+v"(hc[6][1]), "+v"(hc[6][2]), "+v"(hc[6][3]),
                          "+v"(hc[7][0]), "+v"(hc[7][1]), "+v"(hc[7][2]), "+v"(hc[7][3]));
        asm volatile("" : "+v"(hd01[0]), "+v"(hd01[1]), "+v"(hd01[2]), "+v"(hd01[3]),
                          "+v"(hd23[0]), "+v"(hd23[1]), "+v"(hd23[2]), "+v"(hd23[3]),
                          "+v"(b4v.x), "+v"(b4v.y), "+v"(b4v.z), "+v"(b4v.w));

        float v[RB][4];
#pragma unroll
        for (int r = 0; r < RB; ++r) {
            v[r][0] = cur[r].x; v[r][1] = cur[r].y; v[r][2] = cur[r].z; v[r][3] = cur[r].w;
        }
        // stage 0 (stride 1): pairs (e0,e1),(e2,e3)
#pragma unroll
        for (int r = 0; r < RB; ++r) {
            float a0 = flo(hc[0][0]) * v[r][0] + fhi(hc[0][0]) * v[r][1];
            float a1 = flo(hc[0][1]) * v[r][1] + fhi(hc[0][1]) * v[r][0];
            float a2 = flo(hc[0][2]) * v[r][2] + fhi(hc[0][2]) * v[r][3];
            float a3 = flo(hc[0][3]) * v[r][3] + fhi(hc[0][3]) * v[r][2];
            v[r][0] = a0; v[r][1] = a1; v[r][2] = a2; v[r][3] = a3;
        }
        // stage 1 (stride 2): pairs (e0,e2),(e1,e3)
#pragma unroll
        for (int r = 0; r < RB; ++r) {
            float a0 = flo(hc[1][0]) * v[r][0] + fhi(hc[1][0]) * v[r][2];
            float a1 = flo(hc[1][1]) * v[r][1] + fhi(hc[1][1]) * v[r][3];
            float a2 = flo(hc[1][2]) * v[r][2] + fhi(hc[1][2]) * v[r][0];
            float a3 = flo(hc[1][3]) * v[r][3] + fhi(hc[1][3]) * v[r][1];
            v[r][0] = a0; v[r][1] = a1; v[r][2] = a2; v[r][3] = a3;
        }
        // stage 2: lane^1 (quad_perm [1,0,3,2])
#pragma unroll
        for (int r = 0; r < RB; ++r)
#pragma unroll
            for (int e = 0; e < 4; ++e) {
                const float o = dppf<0xB1>(v[r][e]);
                v[r][e] = flo(hc[2][e]) * v[r][e] + fhi(hc[2][e]) * o;
            }
        // stage 3: lane^2 (quad_perm [2,3,0,1])
#pragma unroll
        for (int r = 0; r < RB; ++r)
#pragma unroll
            for (int e = 0; e < 4; ++e) {
                const float o = dppf<0x4E>(v[r][e]);
                v[r][e] = flo(hc[3][e]) * v[r][e] + fhi(hc[3][e]) * o;
            }
        // stage 4: lane^4 (two DPP shifts + select)
#pragma unroll
        for (int r = 0; r < RB; ++r)
#pragma unroll
            for (int e = 0; e < 4; ++e) {
                const float o = xor4f(v[r][e], b4set);
                v[r][e] = flo(hc[4][e]) * v[r][e] + fhi(hc[4][e]) * o;
            }
        // stage 5: lane^8 (row_ror:8)
#pragma unroll
        for (int r = 0; r < RB; ++r)
#pragma unroll
            for (int e = 0; e < 4; ++e) {
                const float o = dppf<0x128>(v[r][e]);
                v[r][e] = flo(hc[5][e]) * v[r][e] + fhi(hc[5][e]) * o;
            }
        // stage 6: lane^16 (permlane16_swap)
#pragma unroll
        for (int r = 0; r < RB; ++r)
#pragma unroll
            for (int e = 0; e < 4; ++e) {
                const float o = xor16f(v[r][e], hi16);
                v[r][e] = flo(hc[6][e]) * v[r][e] + fhi(hc[6][e]) * o;
            }
        // stage 7: lane^32 (permlane32_swap)
#pragma unroll
        for (int r = 0; r < RB; ++r)
#pragma unroll
            for (int e = 0; e < 4; ++e) {
                const float o = xor32f(v[r][e], hi32, bpaddr);
                v[r][e] = flo(hc[7][e]) * v[r][e] + fhi(hc[7][e]) * o;
            }
        // merged stages 8+9: one LDS roundtrip, one barrier per batch (4 rows).
        const int buf = b & 1;
#pragma unroll
        for (int r = 0; r < RB; ++r)
            lds[buf][r][tid] = make_float4(v[r][0], v[r][1], v[r][2], v[r][3]);
        __syncthreads();

        // Prefetch next batch (R9 position: after the barrier; R10/R11 moves
        // both regressed via L3-residency loss).
        if (b + 1 < NB) {
#pragma unroll
            for (int r = 0; r < RB; ++r)
                cur[r] = *reinterpret_cast<const float4*>(
                    x + (size_t)(rowbase + (b + 1) * RB + r) * 1024 + n0);
        }

#pragma unroll
        for (int r = 0; r < RB; ++r) {
            const float4 o64  = lds[buf][r][tid ^ 64];
            const float4 o128 = lds[buf][r][tid ^ 128];
            const float4 o192 = lds[buf][r][tid ^ 192];
            f32x4 s;
            s.x = flo(hd01[0])*v[r][0] + fhi(hd01[0])*o64.x + flo(hd23[0])*o128.x + fhi(hd23[0])*o192.x + b4v.x;
            s.y = flo(hd01[1])*v[r][1] + fhi(hd01[1])*o64.y + flo(hd23[1])*o128.y + fhi(hd23[1])*o192.y + b4v.y;
            s.z = flo(hd01[2])*v[r][2] + fhi(hd01[2])*o64.z + flo(hd23[2])*o128.z + fhi(hd23[2])*o192.z + b4v.z;
            s.w = flo(hd01[3])*v[r][3] + fhi(hd01[3])*o64.w + flo(hd23[3])*o128.w + fhi(hd23[3])*o192.w + b4v.w;
            // R13: nontemporal store -- skip the write-allocate path.
            __builtin_nontemporal_store(
                s, reinterpret_cast<f32x4*>(out + (size_t)(rowbase + b * RB + r) * 1024 + n0));
        }
        // Race-freedom (R3..R9 argument): reads of lds[buf] (batch b) precede
        // the __syncthreads of batch b+1; writes to lds[buf] recur at batch b+2,
        // after that barrier. No overlap.
    }
}

extern "C" void kernel_launch(void* const* d_in, const int* in_sizes, int n_in,
                              void* d_out, int out_size, void* d_ws, size_t ws_size,
                              hipStream_t stream) {
    const float* x    = (const float*)d_in[0];
    const float* tw   = (const float*)d_in[1];
    const float* bias = (const float*)d_in[2];
    float* outp = (float*)d_out;
    unsigned* ws = (unsigned*)d_ws;
    dim3 grid(32768 / RPB);   // 2048 blocks
    dim3 block(256);
    if (ws_size >= WS_WORDS * 256 * sizeof(unsigned)) {
        hipLaunchKernelGGL(coeff_prep_kernel, dim3(1), block, 0, stream, tw, ws);
        hipLaunchKernelGGL((butterfly_kernel<true>), grid, block, 0, stream,
                           x, tw, bias, outp, ws);
    } else {
        hipLaunchKernelGGL((butterfly_kernel<false>), grid, block, 0, stream,
                           x, tw, bias, outp, ws);
    }
}